// Round 1
// baseline (477.044 us; speedup 1.0000x reference)
//
#include <hip/hip_runtime.h>
#include <hip/hip_bf16.h>
#include <stdint.h>

#define M_DIM 8192
#define N_DIM 4096
#define K_DIM 4096
#define RANK  16

#define BM 128
#define BN 128
#define BK 64

typedef __attribute__((ext_vector_type(8))) __bf16 bf16x8;
typedef __attribute__((ext_vector_type(4))) float  f32x4;

__device__ __forceinline__ unsigned short f2bf(float f) {
    union { float f; uint32_t u; } c; c.f = f;
    uint32_t b = c.u;
    b += 0x7FFFu + ((b >> 16) & 1u);   // round-to-nearest-even (finite data)
    return (unsigned short)(b >> 16);
}

// ---------------- x fp32 -> bf16 ----------------
__global__ void convert_x_kernel(const float* __restrict__ x,
                                 unsigned short* __restrict__ xb, int n4) {
    int idx = blockIdx.x * blockDim.x + threadIdx.x;
    int stride = gridDim.x * blockDim.x;
    for (int i = idx; i < n4; i += stride) {
        float4 v = reinterpret_cast<const float4*>(x)[i];
        ushort4 o;
        o.x = f2bf(v.x); o.y = f2bf(v.y); o.z = f2bf(v.z); o.w = f2bf(v.w);
        reinterpret_cast<ushort4*>(xb)[i] = o;
    }
}

// ---------------- W_eff = tile(wp,4) + s * B@A, stored bf16 [N][K] ----------------
__global__ void build_weff_kernel(const float* __restrict__ wp,   // [4096][1024]
                                  const float* __restrict__ lA,   // [16][4096]
                                  const float* __restrict__ lB,   // [4096][16]
                                  const int*   __restrict__ scaling,
                                  unsigned short* __restrict__ weff) { // [4096][4096]
    int o = blockIdx.x;               // one output row per block
    float s = (float)scaling[0];
    float b[RANK];
#pragma unroll
    for (int r = 0; r < RANK; ++r) b[r] = lB[o * RANK + r] * s;
    int tid = threadIdx.x;
#pragma unroll
    for (int ii = 0; ii < 16; ++ii) {
        int i = tid + ii * 256;
        float acc = wp[o * 1024 + (i & 1023)];
#pragma unroll
        for (int r = 0; r < RANK; ++r) acc = fmaf(b[r], lA[r * 4096 + i], acc);
        weff[(size_t)o * 4096 + i] = f2bf(acc);
    }
}

// ---------------- bf16 GEMM: C[m][n] = sum_k A[m][k] * B[n][k] ----------------
// m97-verified structure: 128x128 tile, BK=64, 4 waves (2x2), global_load_lds w=16,
// 16x16x32 bf16 MFMA, 2-barrier K-loop.
__global__ __launch_bounds__(256) void gemm_kernel(
    const unsigned short* __restrict__ A,   // x bf16 [8192][4096]
    const unsigned short* __restrict__ B,   // W_eff bf16 [4096][4096]
    float* __restrict__ C)                  // [8192][4096] fp32
{
    __shared__ unsigned short As[BM * BK];
    __shared__ unsigned short Bs[BN * BK];

    const int tid  = threadIdx.x;
    const int lane = tid & 63;
    const int wave = tid >> 6;
    const int wr = wave >> 1;      // 2x2 wave grid, each wave owns 64x64
    const int wc = wave & 1;

    const int bid = blockIdx.x;
    const int bm = bid >> 5;       // N_DIM/BN = 32 tiles, n fastest
    const int bn = bid & 31;
    const int m0 = bm * BM;
    const int n0 = bn * BN;

    // staging: instr j, thread t covers LDS elements (j*256+t)*8 .. +7
    // -> row = (j*256+t)>>3, col = (t&7)*8 of the [128][64] tile
    const int scol    = (tid & 7) * 8;
    const int ldsbase = (tid & ~63) * 8;   // wave-uniform element base (+ j*2048)

    const unsigned short* gA = A + (size_t)m0 * K_DIM + scol;
    const unsigned short* gB = B + (size_t)n0 * K_DIM + scol;

    f32x4 acc[4][4];
#pragma unroll
    for (int i = 0; i < 4; ++i)
#pragma unroll
        for (int j = 0; j < 4; ++j) acc[i][j] = (f32x4){0.f, 0.f, 0.f, 0.f};

    const int arow = wr * 64 + (lane & 15);  // + mf*16
    const int brow = wc * 64 + (lane & 15);  // + nf*16
    const int koff = (lane >> 4) * 8;        // + kc*32

    for (int kt = 0; kt < K_DIM; kt += BK) {
#pragma unroll
        for (int j = 0; j < 4; ++j) {
            int row = (j * 256 + tid) >> 3;
            __builtin_amdgcn_global_load_lds(
                (const __attribute__((address_space(1))) void*)(gA + (size_t)row * K_DIM + kt),
                (__attribute__((address_space(3))) void*)(As + ldsbase + j * 2048),
                16, 0, 0);
        }
#pragma unroll
        for (int j = 0; j < 4; ++j) {
            int row = (j * 256 + tid) >> 3;
            __builtin_amdgcn_global_load_lds(
                (const __attribute__((address_space(1))) void*)(gB + (size_t)row * K_DIM + kt),
                (__attribute__((address_space(3))) void*)(Bs + ldsbase + j * 2048),
                16, 0, 0);
        }
        __syncthreads();   // compiler emits vmcnt(0) drain before barrier

#pragma unroll
        for (int kc = 0; kc < 2; ++kc) {
            bf16x8 af[4], bfr[4];
#pragma unroll
            for (int mf = 0; mf < 4; ++mf)
                af[mf] = *reinterpret_cast<const bf16x8*>(
                    &As[(arow + mf * 16) * BK + kc * 32 + koff]);
#pragma unroll
            for (int nf = 0; nf < 4; ++nf)
                bfr[nf] = *reinterpret_cast<const bf16x8*>(
                    &Bs[(brow + nf * 16) * BK + kc * 32 + koff]);
#pragma unroll
            for (int mf = 0; mf < 4; ++mf)
#pragma unroll
                for (int nf = 0; nf < 4; ++nf)
                    acc[mf][nf] = __builtin_amdgcn_mfma_f32_16x16x32_bf16(
                        af[mf], bfr[nf], acc[mf][nf], 0, 0, 0);
        }
        __syncthreads();
    }

    // epilogue: D mapping col = lane&15, row = (lane>>4)*4 + reg
    const int crow0 = m0 + wr * 64 + (lane >> 4) * 4;
    const int ccol0 = n0 + wc * 64 + (lane & 15);
#pragma unroll
    for (int mf = 0; mf < 4; ++mf)
#pragma unroll
        for (int nf = 0; nf < 4; ++nf)
#pragma unroll
            for (int r = 0; r < 4; ++r)
                C[(size_t)(crow0 + mf * 16 + r) * N_DIM + ccol0 + nf * 16] =
                    acc[mf][nf][r];
}

extern "C" void kernel_launch(void* const* d_in, const int* in_sizes, int n_in,
                              void* d_out, int out_size, void* d_ws, size_t ws_size,
                              hipStream_t stream) {
    const float* x  = (const float*)d_in[0];
    const float* wp = (const float*)d_in[1];
    const float* lA = (const float*)d_in[2];
    const float* lB = (const float*)d_in[3];
    const int*   sc = (const int*)d_in[4];
    float* out = (float*)d_out;

    // ws layout: [0, 64MB) x_bf16 ; [64MB, 96MB) W_eff bf16
    unsigned short* xb   = (unsigned short*)d_ws;
    unsigned short* weff = (unsigned short*)d_ws + (size_t)M_DIM * K_DIM;

    convert_x_kernel<<<2048, 256, 0, stream>>>(x, xb, (M_DIM * K_DIM) / 4);
    build_weff_kernel<<<N_DIM, 256, 0, stream>>>(wp, lA, lB, sc, weff);

    int grid = (M_DIM / BM) * (N_DIM / BN);   // 64 * 32 = 2048
    gemm_kernel<<<grid, 256, 0, stream>>>(xb, weff, out);
}

// Round 2
// 332.365 us; speedup vs baseline: 1.4353x; 1.4353x over previous
//
#include <hip/hip_runtime.h>
#include <hip/hip_bf16.h>
#include <stdint.h>

#define M_DIM 8192
#define N_DIM 4096
#define K_DIM 4096
#define RANK  16

#define BM 256
#define BN 256
#define BK 64
#define NKT (K_DIM / BK)   // 64 K-tiles

typedef __attribute__((ext_vector_type(8))) __bf16 bf16x8;
typedef __attribute__((ext_vector_type(4))) float  f32x4;

__device__ __forceinline__ unsigned short f2bf(float f) {
    union { float f; uint32_t u; } c; c.f = f;
    uint32_t b = c.u;
    b += 0x7FFFu + ((b >> 16) & 1u);   // RNE (finite data)
    return (unsigned short)(b >> 16);
}

// ---------------- x fp32 -> bf16 ----------------
__global__ void convert_x_kernel(const float* __restrict__ x,
                                 unsigned short* __restrict__ xb, int n4) {
    int idx = blockIdx.x * blockDim.x + threadIdx.x;
    int stride = gridDim.x * blockDim.x;
    for (int i = idx; i < n4; i += stride) {
        float4 v = reinterpret_cast<const float4*>(x)[i];
        ushort4 o;
        o.x = f2bf(v.x); o.y = f2bf(v.y); o.z = f2bf(v.z); o.w = f2bf(v.w);
        reinterpret_cast<ushort4*>(xb)[i] = o;
    }
}

// ---------------- W_eff = tile(wp,4) + s * B@A, stored bf16 [N][K] ----------------
__global__ void build_weff_kernel(const float* __restrict__ wp,   // [4096][1024]
                                  const float* __restrict__ lA,   // [16][4096]
                                  const float* __restrict__ lB,   // [4096][16]
                                  const int*   __restrict__ scaling,
                                  unsigned short* __restrict__ weff) { // [4096][4096]
    int o = blockIdx.x;
    float s = (float)scaling[0];
    float b[RANK];
#pragma unroll
    for (int r = 0; r < RANK; ++r) b[r] = lB[o * RANK + r] * s;
    int tid = threadIdx.x;
#pragma unroll
    for (int ii = 0; ii < 16; ++ii) {
        int i = tid + ii * 256;
        float acc = wp[o * 1024 + (i & 1023)];
#pragma unroll
        for (int r = 0; r < RANK; ++r) acc = fmaf(b[r], lA[r * 4096 + i], acc);
        weff[(size_t)o * 4096 + i] = f2bf(acc);
    }
}

// ---------------- 256x256 8-phase bf16 GEMM ----------------
// C[m][n] = sum_k A[m,k] * B[n,k].  8 waves (2M x 4N), per-wave 128x64 output.
// LDS per buf: A [mh][wr][64][64], B [nh][wc][32][64]; 2 bufs = 128 KiB.
// Swizzle: colbyte ^= (row&7)<<4 ; applied via pre-swizzled global SOURCE on
// the linear global_load_lds dest + same XOR on ds_read addr (involution).

template<int MH, int NH>
__device__ __forceinline__ void mfma_quad(const bf16x8 (&a)[4][2], const bf16x8 (&b)[2][2],
                                          f32x4 (&acc)[8][4]) {
#pragma unroll
    for (int kc = 0; kc < 2; ++kc)
#pragma unroll
        for (int mf = 0; mf < 4; ++mf)
#pragma unroll
            for (int nf = 0; nf < 2; ++nf)
                acc[MH * 4 + mf][NH * 2 + nf] = __builtin_amdgcn_mfma_f32_16x16x32_bf16(
                    a[mf][kc], b[nf][kc], acc[MH * 4 + mf][NH * 2 + nf], 0, 0, 0);
}

__global__ __launch_bounds__(512, 2) void gemm_kernel(
    const unsigned short* __restrict__ A,   // x bf16 [8192][4096]
    const unsigned short* __restrict__ B,   // W_eff bf16 [4096][4096]
    float* __restrict__ C)                  // [8192][4096] fp32
{
    __shared__ __align__(16) char lds[131072];

    const int tid  = threadIdx.x;
    const int lane = tid & 63;
    const int wave = tid >> 6;
    const int wr = wave >> 2;          // 0..1 (M)
    const int wc = wave & 3;           // 0..3 (N)

    // bijective XCD swizzle: 512 blocks, 8 XCDs
    const int bid = blockIdx.x;
    const int swz = (bid & 7) * 64 + (bid >> 3);
    const int bm = swz >> 4;           // 0..31
    const int bn = swz & 15;           // 0..15
    const int m0 = bm * BM;
    const int n0 = bn * BN;

    // ---- staging addressing (per-thread, j-independent) ----
    const int srccol = 8 * ((tid & 7) ^ ((tid >> 3) & 7));   // pre-swizzled col (elems)
    const int wub    = (tid & ~63) * 16;                     // wave-uniform LDS byte base
    const unsigned short* Ag = A + (size_t)(m0 + (tid >> 3)) * K_DIM + srccol;
    const unsigned short* Bg = B + (size_t)(n0 + (tid >> 8) * 64 + ((tid >> 3) & 31)) * K_DIM + srccol;

#define STAGE_A(buf, mh, kt) do { \
    __builtin_amdgcn_global_load_lds( \
        (const __attribute__((address_space(1))) void*)(Ag + (size_t)((mh) * 64) * K_DIM + (size_t)(kt) * 64), \
        (__attribute__((address_space(3))) void*)(lds + (buf) * 65536 + (mh) * 16384 + wub), 16, 0, 0); \
    __builtin_amdgcn_global_load_lds( \
        (const __attribute__((address_space(1))) void*)(Ag + (size_t)(128 + (mh) * 64) * K_DIM + (size_t)(kt) * 64), \
        (__attribute__((address_space(3))) void*)(lds + (buf) * 65536 + (mh) * 16384 + 8192 + wub), 16, 0, 0); \
} while (0)

#define STAGE_B(buf, nh, kt) do { \
    __builtin_amdgcn_global_load_lds( \
        (const __attribute__((address_space(1))) void*)(Bg + (size_t)((nh) * 32) * K_DIM + (size_t)(kt) * 64), \
        (__attribute__((address_space(3))) void*)(lds + (buf) * 65536 + 32768 + (nh) * 16384 + wub), 16, 0, 0); \
    __builtin_amdgcn_global_load_lds( \
        (const __attribute__((address_space(1))) void*)(Bg + (size_t)(128 + (nh) * 32) * K_DIM + (size_t)(kt) * 64), \
        (__attribute__((address_space(3))) void*)(lds + (buf) * 65536 + 32768 + (nh) * 16384 + 8192 + wub), 16, 0, 0); \
} while (0)

    // ---- read-side addressing ----
    const int wrA   = wr * 8192;
    const int wcB   = wc * 4096;
    const int rdrow = (lane & 15) * 128;           // row byte offset
    const int rdxor = (lane & 7) << 4;             // swizzle XOR (row&7)<<4
    const int rdg   = (lane >> 4) * 16;            // 16B slot

#define RD_A(dst, buf, mh) do { \
    _Pragma("unroll") for (int mf = 0; mf < 4; ++mf) \
    _Pragma("unroll") for (int kc = 0; kc < 2; ++kc) \
        dst[mf][kc] = *(const bf16x8*)(lds + (buf) * 65536 + (mh) * 16384 + wrA + rdrow + mf * 2048 + ((kc * 64 + rdg) ^ rdxor)); \
} while (0)

#define RD_B(dst, buf, nh) do { \
    _Pragma("unroll") for (int nf = 0; nf < 2; ++nf) \
    _Pragma("unroll") for (int kc = 0; kc < 2; ++kc) \
        dst[nf][kc] = *(const bf16x8*)(lds + (buf) * 65536 + 32768 + (nh) * 16384 + wcB + rdrow + nf * 2048 + ((kc * 64 + rdg) ^ rdxor)); \
} while (0)

#define PH_TAIL(QUAD) \
    __builtin_amdgcn_s_barrier(); \
    asm volatile("s_waitcnt lgkmcnt(0)" ::: "memory"); \
    __builtin_amdgcn_s_setprio(1); \
    QUAD; \
    __builtin_amdgcn_s_setprio(0);

    f32x4 acc[8][4];
#pragma unroll
    for (int i = 0; i < 8; ++i)
#pragma unroll
        for (int j = 0; j < 4; ++j) acc[i][j] = (f32x4){0.f, 0.f, 0.f, 0.f};

    bf16x8 afr[4][2];
    bf16x8 bfr[2][2];

    // ---- prologue: tile0 (4 halves) + tile1 (A0,B1) ----
    STAGE_A(0, 0, 0); STAGE_B(0, 1, 0); STAGE_A(0, 1, 0); STAGE_B(0, 0, 0);
    STAGE_A(1, 0, 1); STAGE_B(1, 1, 1);
    asm volatile("s_waitcnt vmcnt(4)" ::: "memory");
    __builtin_amdgcn_s_barrier();

    for (int it = 0; it < NKT / 2; ++it) {
        const int k1 = 2 * it + 1;
        const int k2 = (2 * it + 2) & (NKT - 1);   // dummy re-stage on last iter (safe)
        const int k3 = (2 * it + 3) & (NKT - 1);

        // P1: buf0 quad(0,0)
        RD_A(afr, 0, 0); RD_B(bfr, 0, 0);
        STAGE_A(1, 1, k1);
        PH_TAIL((mfma_quad<0, 0>(afr, bfr, acc)));
        __builtin_amdgcn_s_barrier();
        // P2: buf0 quad(0,1)
        RD_B(bfr, 0, 1);
        STAGE_B(1, 0, k1);
        PH_TAIL((mfma_quad<0, 1>(afr, bfr, acc)));
        __builtin_amdgcn_s_barrier();
        // P3: buf0 quad(1,1)
        RD_A(afr, 0, 1);
        STAGE_A(0, 0, k2);
        PH_TAIL((mfma_quad<1, 1>(afr, bfr, acc)));
        __builtin_amdgcn_s_barrier();
        // P4: buf0 quad(1,0)  + counted vmcnt (buf1 tile k1 complete after barrier)
        RD_B(bfr, 0, 0);
        STAGE_B(0, 1, k2);
        PH_TAIL((mfma_quad<1, 0>(afr, bfr, acc)));
        asm volatile("s_waitcnt vmcnt(4)" ::: "memory");
        __builtin_amdgcn_s_barrier();
        // P5: buf1 quad(0,0)
        RD_A(afr, 1, 0); RD_B(bfr, 1, 0);
        STAGE_A(0, 1, k2);
        PH_TAIL((mfma_quad<0, 0>(afr, bfr, acc)));
        __builtin_amdgcn_s_barrier();
        // P6: buf1 quad(0,1)
        RD_B(bfr, 1, 1);
        STAGE_B(0, 0, k2);
        PH_TAIL((mfma_quad<0, 1>(afr, bfr, acc)));
        __builtin_amdgcn_s_barrier();
        // P7: buf1 quad(1,1)
        RD_A(afr, 1, 1);
        STAGE_A(1, 0, k3);
        PH_TAIL((mfma_quad<1, 1>(afr, bfr, acc)));
        __builtin_amdgcn_s_barrier();
        // P8: buf1 quad(1,0) + counted vmcnt (buf0 tile k2 complete after barrier)
        RD_B(bfr, 1, 0);
        STAGE_B(1, 1, k3);
        PH_TAIL((mfma_quad<1, 0>(afr, bfr, acc)));
        asm volatile("s_waitcnt vmcnt(4)" ::: "memory");
        __builtin_amdgcn_s_barrier();
    }

    // ---- epilogue: C write. D frag: col = lane&15, row = (lane>>4)*4 + r ----
    const int crow = m0 + wr * 128 + (lane >> 4) * 4;
    const int ccol = n0 + wc * 64 + (lane & 15);
#pragma unroll
    for (int mi = 0; mi < 8; ++mi)
#pragma unroll
        for (int ni = 0; ni < 4; ++ni)
#pragma unroll
            for (int r = 0; r < 4; ++r)
                C[(size_t)(crow + mi * 16 + r) * N_DIM + ccol + ni * 16] = acc[mi][ni][r];

#undef STAGE_A
#undef STAGE_B
#undef RD_A
#undef RD_B
#undef PH_TAIL
}

extern "C" void kernel_launch(void* const* d_in, const int* in_sizes, int n_in,
                              void* d_out, int out_size, void* d_ws, size_t ws_size,
                              hipStream_t stream) {
    const float* x  = (const float*)d_in[0];
    const float* wp = (const float*)d_in[1];
    const float* lA = (const float*)d_in[2];
    const float* lB = (const float*)d_in[3];
    const int*   sc = (const int*)d_in[4];
    float* out = (float*)d_out;

    unsigned short* xb   = (unsigned short*)d_ws;                               // 64 MB
    unsigned short* weff = (unsigned short*)d_ws + (size_t)M_DIM * K_DIM;       // 32 MB

    convert_x_kernel<<<2048, 256, 0, stream>>>(x, xb, (M_DIM * K_DIM) / 4);
    build_weff_kernel<<<N_DIM, 256, 0, stream>>>(wp, lA, lB, sc, weff);

    int grid = (M_DIM / BM) * (N_DIM / BN);   // 32 * 16 = 512
    gemm_kernel<<<grid, 512, 0, stream>>>(xb, weff, out);
}